// Round 4
// baseline (541.114 us; speedup 1.0000x reference)
//
#include <hip/hip_runtime.h>

#define NROW 27
#define EDIM 5120
#define QKVDIM 15360
#define HD 1280

typedef __attribute__((ext_vector_type(8))) short bf16x8;
typedef __attribute__((ext_vector_type(4))) float f32x4;

__device__ __forceinline__ short f2bf(float x) {
    unsigned u = __builtin_bit_cast(unsigned, x);
    u = (u + 0x7FFFu + ((u >> 16) & 1u)) >> 16;
    return (short)u;
}
__device__ __forceinline__ float bf2f(short h) {
    unsigned u = ((unsigned)(unsigned short)h) << 16;
    return __builtin_bit_cast(float, u);
}

// Convert 8 fp32 (from LDS) -> bf16 hi + lo fragments
__device__ __forceinline__ void cvt8(const float* w, bf16x8& hi, bf16x8& lo) {
    float4 a = *(const float4*)w;
    float4 b = *(const float4*)(w + 4);
    float f[8] = {a.x, a.y, a.z, a.w, b.x, b.y, b.z, b.w};
    #pragma unroll
    for (int j = 0; j < 8; ++j) {
        short h = f2bf(f[j]);
        hi[j] = h;
        lo[j] = f2bf(f[j] - bf2f(h));
    }
}

// ---------------------------------------------------------------------------
// Cp[ky][27][Ntot] = X[27,Kblk] @ W[Ntot,Kblk]^T, bf16 hi/lo split MFMA
// (Ahi*Bhi + Ahi*Blo + Alo*Bhi ~ fp32 accuracy).
// W staged fp32 -> LDS via global_load_lds (16B, no VGPR round-trip),
// converted to bf16 at fragment read. X pre-converted to bf16 hi/lo in
// global (L2-resident), A-fragments loaded directly.
// Block: Ntile=128 x Mtile=32(27), KC=64, 256 thr = 4 waves, 32 KB LDS
// -> 5 blocks/CU. Wave w owns n in [32w,32w+32): 2x2 tiles of 16x16x32.
// ---------------------------------------------------------------------------
#define KC 64

__global__ __launch_bounds__(256)
void gemm_glds(const short* __restrict__ Xhi, const short* __restrict__ Xlo,
               const float* __restrict__ W, float* __restrict__ Cp,
               int K, int Ntot, int Kblk)
{
    __shared__ float Wf[128][KC];   // 32 KB, rows dense (lane-order constraint)

    const int tid = threadIdx.x;
    const int n0 = blockIdx.x * 128;
    const int k0 = blockIdx.y * Kblk;

    const int lane = tid & 63;
    const int wv   = tid >> 6;
    const int lm   = lane & 15;
    const int q8   = (lane >> 4) * 8;
    const int rA1  = (lm + 16 < NROW) ? lm + 16 : 0;  // clamped 2nd A row

    f32x4 acc[2][2] = {};

    // async W loader: inst i covers seg s = i*256+tid -> row = i*16+(tid>>4),
    // kseg = tid&15 (16B units). LDS dst = Wf + s*16 bytes.
    const float* wp = W + (size_t)(n0 + (tid >> 4)) * K + k0 + 4 * (tid & 15);
    char* lds0 = (char*)&Wf[0][0] + tid * 16;

    // A-fragment base pointers (bf16, global / L2)
    const short* pAh0 = Xhi + (size_t)lm  * K + k0;
    const short* pAh1 = Xhi + (size_t)rA1 * K + k0;
    const short* pAl0 = Xlo + (size_t)lm  * K + k0;
    const short* pAl1 = Xlo + (size_t)rA1 * K + k0;

    for (int kc = 0; kc < Kblk; kc += KC) {
        #pragma unroll
        for (int i = 0; i < 8; ++i)
            __builtin_amdgcn_global_load_lds(
                (const __attribute__((address_space(1))) unsigned*)(wp + (size_t)i * 16 * K),
                (__attribute__((address_space(3))) unsigned*)(lds0 + i * 4096),
                16, 0, 0);
        __syncthreads();

        #pragma unroll
        for (int s = 0; s < 2; ++s) {
            const int ko = 32 * s + q8;
            bf16x8 ah0 = *(const bf16x8*)(pAh0 + ko);
            bf16x8 ah1 = *(const bf16x8*)(pAh1 + ko);
            bf16x8 al0 = *(const bf16x8*)(pAl0 + ko);
            bf16x8 al1 = *(const bf16x8*)(pAl1 + ko);

            bf16x8 bh0, bl0, bh1, bl1;
            cvt8(&Wf[32 * wv + lm][ko],      bh0, bl0);
            cvt8(&Wf[32 * wv + 16 + lm][ko], bh1, bl1);

            acc[0][0] = __builtin_amdgcn_mfma_f32_16x16x32_bf16(ah0, bh0, acc[0][0], 0, 0, 0);
            acc[0][0] = __builtin_amdgcn_mfma_f32_16x16x32_bf16(ah0, bl0, acc[0][0], 0, 0, 0);
            acc[0][0] = __builtin_amdgcn_mfma_f32_16x16x32_bf16(al0, bh0, acc[0][0], 0, 0, 0);

            acc[0][1] = __builtin_amdgcn_mfma_f32_16x16x32_bf16(ah0, bh1, acc[0][1], 0, 0, 0);
            acc[0][1] = __builtin_amdgcn_mfma_f32_16x16x32_bf16(ah0, bl1, acc[0][1], 0, 0, 0);
            acc[0][1] = __builtin_amdgcn_mfma_f32_16x16x32_bf16(al0, bh1, acc[0][1], 0, 0, 0);

            acc[1][0] = __builtin_amdgcn_mfma_f32_16x16x32_bf16(ah1, bh0, acc[1][0], 0, 0, 0);
            acc[1][0] = __builtin_amdgcn_mfma_f32_16x16x32_bf16(ah1, bl0, acc[1][0], 0, 0, 0);
            acc[1][0] = __builtin_amdgcn_mfma_f32_16x16x32_bf16(al1, bh0, acc[1][0], 0, 0, 0);

            acc[1][1] = __builtin_amdgcn_mfma_f32_16x16x32_bf16(ah1, bh1, acc[1][1], 0, 0, 0);
            acc[1][1] = __builtin_amdgcn_mfma_f32_16x16x32_bf16(ah1, bl1, acc[1][1], 0, 0, 0);
            acc[1][1] = __builtin_amdgcn_mfma_f32_16x16x32_bf16(al1, bh1, acc[1][1], 0, 0, 0);
        }
        __syncthreads();

        wp += KC;
        pAh0 += KC; pAh1 += KC; pAl0 += KC; pAl1 += KC;
    }

    const size_t base = (size_t)blockIdx.y * NROW * Ntot;
    #pragma unroll
    for (int mi = 0; mi < 2; ++mi) {
        #pragma unroll
        for (int r = 0; r < 4; ++r) {
            const int m = mi * 16 + (lane >> 4) * 4 + r;
            if (m < NROW) {
                #pragma unroll
                for (int ni = 0; ni < 2; ++ni) {
                    const int n = n0 + 32 * wv + ni * 16 + lm;
                    Cp[base + (size_t)m * Ntot + n] = acc[mi][ni][r];
                }
            }
        }
    }
}

// ---------------------------------------------------------------------------
// fp32 -> bf16 hi/lo arrays (X and similar small tensors)
// ---------------------------------------------------------------------------
__global__ __launch_bounds__(256)
void convert_bf(const float* __restrict__ x, short* __restrict__ hi,
                short* __restrict__ lo, int n4)
{
    const int idx = blockIdx.x * 256 + threadIdx.x;
    if (idx >= n4) return;
    float4 v = ((const float4*)x)[idx];
    float f[4] = {v.x, v.y, v.z, v.w};
    short4 h, l;
    short hh[4], ll[4];
    #pragma unroll
    for (int j = 0; j < 4; ++j) {
        short t = f2bf(f[j]);
        hh[j] = t;
        ll[j] = f2bf(f[j] - bf2f(t));
    }
    h.x = hh[0]; h.y = hh[1]; h.z = hh[2]; h.w = hh[3];
    l.x = ll[0]; l.y = ll[1]; l.z = ll[2]; l.w = ll[3];
    ((short4*)hi)[idx] = h;
    ((short4*)lo)[idx] = l;
}

// ---------------------------------------------------------------------------
// out[27,Ntot] = sum_ky Cp[ky] + bias [, * hertz]; optional fused adj block.
// ---------------------------------------------------------------------------
__global__ __launch_bounds__(256)
void reduce_kernel(const float* __restrict__ Cp, const float* __restrict__ bias,
                   float* __restrict__ out, int Ntot, int nky, const int* __restrict__ hz,
                   const float* __restrict__ cr, const float* __restrict__ gb,
                   float* __restrict__ adj)
{
    if (adj && blockIdx.x == gridDim.x - 1) {
        for (int t = threadIdx.x; t < NROW * NROW; t += 256) {
            const int i = t / NROW, j = t % NROW;
            float v = 0.f;
            if (i != j) {
                float z = cr[i] + cr[NROW + j] + gb[0];
                v = 1.0f / (1.0f + expf(-z));
            }
            adj[t] = v;
        }
        return;
    }
    const int idx = blockIdx.x * 256 + threadIdx.x;
    const int total4 = NROW * Ntot / 4;
    if (idx >= total4) return;
    float4 s = ((const float4*)Cp)[idx];
    for (int k = 1; k < nky; ++k) {
        float4 p = ((const float4*)(Cp + (size_t)k * NROW * Ntot))[idx];
        s.x += p.x; s.y += p.y; s.z += p.z; s.w += p.w;
    }
    const int n = (idx * 4) % Ntot;
    float4 b = *(const float4*)(bias + n);
    s.x += b.x; s.y += b.y; s.z += b.z; s.w += b.w;
    if (hz) {
        float h = (float)hz[0] * 0.001f;
        float sc = fminf(fmaxf(h, 0.1f), 1.0f);
        s.x *= sc; s.y *= sc; s.z *= sc; s.w *= sc;
    }
    ((float4*)out)[idx] = s;
}

// ---------------------------------------------------------------------------
// col[i] = node_flat[i]·w_n ; row[i] = hist_flat[i]·w_h
// ---------------------------------------------------------------------------
__global__ __launch_bounds__(256)
void colrow_kernel(const float* __restrict__ node, const float* __restrict__ hist,
                   const float* __restrict__ gw, float* __restrict__ cr)
{
    const int b = blockIdx.x;
    const float* x = (b < NROW) ? node + (size_t)b * EDIM : hist + (size_t)(b - NROW) * EDIM;
    const float* w = (b < NROW) ? gw + EDIM : gw;
    const int tid = threadIdx.x;
    float a = 0.f;
    for (int f = tid; f < EDIM / 4; f += 256) {
        float4 xv = ((const float4*)x)[f];
        float4 wv = ((const float4*)w)[f];
        a += xv.x * wv.x + xv.y * wv.y + xv.z * wv.z + xv.w * wv.w;
    }
    #pragma unroll
    for (int off = 32; off; off >>= 1) a += __shfl_down(a, off);
    __shared__ float red[4];
    if ((tid & 63) == 0) red[tid >> 6] = a;
    __syncthreads();
    if (tid == 0) cr[b] = red[0] + red[1] + red[2] + red[3];
}

// ---------------------------------------------------------------------------
// MHA on qkv[27,15360] (biases already added). One block per (head, query).
// Output written directly as bf16 hi/lo (A operand of the out-proj GEMM).
// ---------------------------------------------------------------------------
__global__ __launch_bounds__(256)
void attn_kernel(const float* __restrict__ qkv, short* __restrict__ Ohi,
                 short* __restrict__ Olo)
{
    __shared__ float qs[HD];
    __shared__ float sc[NROW];
    __shared__ float pr[NROW];
    const int bx = blockIdx.x;
    const int h = bx & 3;
    const int i = bx >> 2;
    const int tid = threadIdx.x;

    const size_t qoff = (size_t)i * QKVDIM + (size_t)h * HD;
    for (int d = tid; d < HD; d += 256) qs[d] = qkv[qoff + d];
    __syncthreads();

    const int wid = tid >> 6, lane = tid & 63;
    for (int j = wid; j < NROW; j += 4) {
        const float* kr = qkv + (size_t)j * QKVDIM + EDIM + (size_t)h * HD;
        float a = 0.f;
        #pragma unroll
        for (int it = 0; it < 5; ++it) {
            int d4 = lane + 64 * it;
            float4 k4 = *(const float4*)(kr + 4 * d4);
            float4 q4 = *(const float4*)(qs + 4 * d4);
            a += q4.x * k4.x + q4.y * k4.y + q4.z * k4.z + q4.w * k4.w;
        }
        #pragma unroll
        for (int off = 32; off; off >>= 1) a += __shfl_down(a, off);
        if (lane == 0) sc[j] = a * 0.02795084971874737f;  // 1/sqrt(1280)
    }
    __syncthreads();

    float mxv = -1e30f;
    for (int j = 0; j < NROW; ++j) mxv = fmaxf(mxv, sc[j]);
    float s = 0.f;
    for (int j = 0; j < NROW; ++j) s += expf(sc[j] - mxv);
    if (tid < NROW) pr[tid] = expf(sc[tid] - mxv) / s;
    __syncthreads();

    for (int d4 = tid; d4 < HD / 4; d4 += 256) {
        float4 o = make_float4(0.f, 0.f, 0.f, 0.f);
        for (int j = 0; j < NROW; ++j) {
            const float4 v4 = *(const float4*)(qkv + (size_t)j * QKVDIM + 2 * EDIM + (size_t)h * HD + 4 * d4);
            const float p = pr[j];
            o.x = fmaf(p, v4.x, o.x);
            o.y = fmaf(p, v4.y, o.y);
            o.z = fmaf(p, v4.z, o.z);
            o.w = fmaf(p, v4.w, o.w);
        }
        float f[4] = {o.x, o.y, o.z, o.w};
        short4 hv, lv;
        short hh[4], ll[4];
        #pragma unroll
        for (int j = 0; j < 4; ++j) {
            short t = f2bf(f[j]);
            hh[j] = t;
            ll[j] = f2bf(f[j] - bf2f(t));
        }
        hv.x = hh[0]; hv.y = hh[1]; hv.z = hh[2]; hv.w = hh[3];
        lv.x = ll[0]; lv.y = ll[1]; lv.z = ll[2]; lv.w = ll[3];
        const size_t oidx = ((size_t)i * EDIM + (size_t)h * HD + 4 * d4) / 4;
        ((short4*)Ohi)[oidx] = hv;
        ((short4*)Olo)[oidx] = lv;
    }
}

extern "C" void kernel_launch(void* const* d_in, const int* in_sizes, int n_in,
                              void* d_out, int out_size, void* d_ws, size_t ws_size,
                              hipStream_t stream)
{
    const float* node = (const float*)d_in[0];
    const float* hist = (const float*)d_in[1];
    const float* gw   = (const float*)d_in[2];
    const float* gb   = (const float*)d_in[3];
    const float* inw  = (const float*)d_in[4];
    const float* inb  = (const float*)d_in[5];
    const float* outw = (const float*)d_in[6];
    const float* outb = (const float*)d_in[7];
    const int*   hz   = (const int*)d_in[8];

    float* out = (float*)d_out;  // [0:138240) attended-out, [138240:138969) adj

    // ws layout
    float* Cp1  = (float*)d_ws;                          // 8 * 27 * 15360 f
    float* qkvf = Cp1 + (size_t)8 * NROW * QKVDIM;       // 27 * 15360 f
    float* Cp2  = qkvf + (size_t)NROW * QKVDIM;          // 16 * 27 * 5120 f
    float* cr   = Cp2 + (size_t)16 * NROW * EDIM;        // 64 f (54 used)
    short* Xhi  = (short*)(cr + 64);                     // 27*5120 shorts each
    short* Xlo  = Xhi + (size_t)NROW * EDIM;
    short* Ohi  = Xlo + (size_t)NROW * EDIM;
    short* Olo  = Ohi + (size_t)NROW * EDIM;

    colrow_kernel<<<54, 256, 0, stream>>>(node, hist, gw, cr);
    convert_bf<<<NROW * EDIM / 4 / 256, 256, 0, stream>>>(node, Xhi, Xlo, NROW * EDIM / 4);

    // qkv = node_flat @ in_w.T (+bias in reduce): N=15360, ksplit=8
    gemm_glds<<<dim3(120, 8), 256, 0, stream>>>(Xhi, Xlo, inw, Cp1, EDIM, QKVDIM, EDIM / 8);
    reduce_kernel<<<NROW * QKVDIM / 4 / 256, 256, 0, stream>>>(
        Cp1, inb, qkvf, QKVDIM, 8, nullptr, nullptr, nullptr, nullptr);

    attn_kernel<<<108, 256, 0, stream>>>(qkvf, Ohi, Olo);

    // out = (O @ out_w.T + out_b) * hertz: N=5120, ksplit=16; +1 block does adj
    gemm_glds<<<dim3(40, 16), 256, 0, stream>>>(Ohi, Olo, outw, Cp2, EDIM, EDIM, EDIM / 16);
    reduce_kernel<<<NROW * EDIM / 4 / 256 + 1, 256, 0, stream>>>(
        Cp2, outb, out, EDIM, 16, hz, cr, gb, out + (size_t)NROW * EDIM);
}